// Round 10
// baseline (127.072 us; speedup 1.0000x reference)
//
#include <hip/hip_runtime.h>
#include <hip/hip_bf16.h>

// GRIN MoE feed-forward, routed top-2, bf16 MFMA grouped GEMM.
// T=4096 tokens, H=512, F=1024, E=8.
// R1: atomic-free routing (counting sort), fused x->bf16 into gating.
// R2: gload_lds(16B, pre-swizzled source).
// R3: counted-vmcnt pipeline, 2-way swizzle, gemm2+combine fusion.
// R7: fused gating+transconv launch.
// R8: gemm1 8-wave 128x128; gemm2 64x128.
// R9: expert-contiguous XCD mapping.
// R10: 4-buffer, stage-3-ahead, vmcnt(6) counted waits on BOTH gemms
//      (lead time 3 steps >= HBM latency; was 2 steps ~600cy < 900cy).

#define T_TOK 4096
#define HDIM  512
#define FDIM  1024
#define NEXP  8
#define MAXT1 72     // 128-granular M tiles
#define MAXT2 136    // 64-granular M tiles

typedef __attribute__((ext_vector_type(8))) __bf16 bf16x8;
typedef __attribute__((ext_vector_type(4))) float  f32x4;
typedef unsigned short ushort_t;

__device__ __forceinline__ unsigned int f2bf(float f) {
  __hip_bfloat16 h = __float2bfloat16(f);
  return (unsigned int)__builtin_bit_cast(unsigned short, h);
}

// global -> LDS direct copy, 16B per lane (wave writes 64 consecutive 16B units)
__device__ __forceinline__ void gload16(const ushort_t* g, ushort_t* l) {
  __builtin_amdgcn_global_load_lds(
      (const __attribute__((address_space(1))) unsigned int*)g,
      (__attribute__((address_space(3))) unsigned int*)l, 16, 0, 0);
}

// ------- fused pre: gating (blocks 0..1023) + weight transconv (rest) --------
__global__ void pre_kernel(const float* __restrict__ x, const float* __restrict__ wg,
                           const float* __restrict__ bg, int4* __restrict__ selraw,
                           ushort_t* __restrict__ xbuf,
                           const float* __restrict__ w1, const float* __restrict__ w3,
                           const float* __restrict__ w2, ushort_t* __restrict__ w1t,
                           ushort_t* __restrict__ w3t, ushort_t* __restrict__ w2t) {
  __shared__ float tile[32][33];
  int blk = blockIdx.x;
  if (blk < 1024) {
    int wv = threadIdx.x >> 6;
    int lane = threadIdx.x & 63;
    int t = blk * 4 + wv;
    const float* xr = x + (size_t)t * HDIM + lane * 8;
    float4 xa = *reinterpret_cast<const float4*>(xr);
    float4 xb = *reinterpret_cast<const float4*>(xr + 4);
    uint4 o;
    o.x = f2bf(xa.x) | (f2bf(xa.y) << 16);
    o.y = f2bf(xa.z) | (f2bf(xa.w) << 16);
    o.z = f2bf(xb.x) | (f2bf(xb.y) << 16);
    o.w = f2bf(xb.z) | (f2bf(xb.w) << 16);
    *reinterpret_cast<uint4*>(xbuf + (size_t)t * HDIM + lane * 8) = o;

    float xv[8] = {xa.x, xa.y, xa.z, xa.w, xb.x, xb.y, xb.z, xb.w};
    float acc[8];
#pragma unroll
    for (int e = 0; e < 8; e++) acc[e] = 0.f;
    int h0 = lane * 8;
#pragma unroll
    for (int j = 0; j < 8; j++) {
      const float4* wr = reinterpret_cast<const float4*>(wg + (size_t)(h0 + j) * 8);
      float4 w0 = wr[0], w1v = wr[1];
      float xj = xv[j];
      acc[0] += xj * w0.x; acc[1] += xj * w0.y; acc[2] += xj * w0.z; acc[3] += xj * w0.w;
      acc[4] += xj * w1v.x; acc[5] += xj * w1v.y; acc[6] += xj * w1v.z; acc[7] += xj * w1v.w;
    }
#pragma unroll
    for (int s = 32; s >= 1; s >>= 1) {
#pragma unroll
      for (int e = 0; e < 8; e++) acc[e] += __shfl_xor(acc[e], s, 64);
    }
    if (lane == 0) {
      float sc[8];
      float mx = -1e30f;
      for (int e = 0; e < 8; e++) { sc[e] = acc[e] + bg[e]; mx = fmaxf(mx, sc[e]); }
      float sum = 0.f;
      for (int e = 0; e < 8; e++) { sc[e] = expf(sc[e] - mx); sum += sc[e]; }
      for (int e = 0; e < 8; e++) sc[e] /= sum;
      int s1 = 0; float mx1 = sc[0];
      for (int e = 1; e < 8; e++) if (sc[e] > mx1) { mx1 = sc[e]; s1 = e; }
      float den1 = 0.f;
      for (int e = 0; e < 8; e++)
        if (!((mx1 - sc[e]) / mx1 > 0.02f)) den1 += expf(sc[e] - mx1);
      float mult1 = 1.0f / den1;
      int s2 = 0; float mx2 = -1e30f;
      for (int e = 0; e < 8; e++) if (e != s1 && sc[e] > mx2) { mx2 = sc[e]; s2 = e; }
      float den2 = 0.f;
      for (int e = 0; e < 8; e++) {
        if (e == s1) continue;
        float fac = fmaxf(sc[e], mx2);
        if (!((mx2 - sc[e]) / fac > 0.02f)) den2 += expf(sc[e] - mx2);
      }
      float mult2 = 1.0f / den2;
      selraw[t] = make_int4(s1, s2, __float_as_int(mult1), __float_as_int(mult2));
    }
    return;
  }
  int b = blk - 1024;
  const float* src; ushort_t* dst; int R, C, rt, ct, e;
  if (b < 8192) {
    src = (b < 4096) ? w1 : w3; dst = (b < 4096) ? w1t : w3t;
    int r = b & 4095; e = r >> 9; r &= 511;
    R = HDIM; C = FDIM; rt = r >> 5; ct = r & 31;
  } else {
    src = w2; dst = w2t;
    int r = b - 8192; e = r >> 9; r &= 511;
    R = FDIM; C = HDIM; rt = r >> 4; ct = r & 15;
  }
  int rb = rt * 32, cb = ct * 32;
  int tr = threadIdx.x >> 3, tc = (threadIdx.x & 7) * 4;
  const float* s = src + ((size_t)e * R + rb + tr) * C + cb + tc;
  float4 v = *reinterpret_cast<const float4*>(s);
  tile[tc + 0][tr] = v.x; tile[tc + 1][tr] = v.y;
  tile[tc + 2][tr] = v.z; tile[tc + 3][tr] = v.w;
  __syncthreads();
  ushort4 ov = {(ushort_t)f2bf(tile[tr][tc]), (ushort_t)f2bf(tile[tr][tc + 1]),
                (ushort_t)f2bf(tile[tr][tc + 2]), (ushort_t)f2bf(tile[tr][tc + 3])};
  *reinterpret_cast<ushort4*>(dst + ((size_t)e * C + cb + tr) * R + rb + tc) = ov;
}

// ------- build: stable counting sort into per-expert lists + schedules -------
__global__ __launch_bounds__(256) void build_kernel(
    const int4* __restrict__ selraw, int* __restrict__ cnt, int* __restrict__ offs,
    int2* __restrict__ sched1, int2* __restrict__ sched2, int* __restrict__ idxl,
    float* __restrict__ wtl) {
  __shared__ int scan[256][8];
  __shared__ int loc[256][8];
  int tid = threadIdx.x;
#pragma unroll
  for (int e = 0; e < 8; e++) { scan[tid][e] = 0; loc[tid][e] = 0; }
  int t0 = tid * (T_TOK / 256);
  int4 raw[T_TOK / 256];
#pragma unroll
  for (int i = 0; i < T_TOK / 256; i++) {
    raw[i] = selraw[t0 + i];
    loc[tid][raw[i].x]++;
    loc[tid][raw[i].y]++;
  }
#pragma unroll
  for (int e = 0; e < 8; e++) scan[tid][e] = loc[tid][e];
  __syncthreads();
  for (int s = 1; s < 256; s <<= 1) {
    int v[8];
    if (tid >= s) {
#pragma unroll
      for (int e = 0; e < 8; e++) v[e] = scan[tid - s][e];
    }
    __syncthreads();
    if (tid >= s) {
#pragma unroll
      for (int e = 0; e < 8; e++) scan[tid][e] += v[e];
    }
    __syncthreads();
  }
  if (tid == 0) {
    int a = 0, t1 = 0, t2 = 0;
    for (int e = 0; e < 8; e++) {
      int ce = scan[255][e];
      cnt[e] = ce; offs[e] = a; a += ce;
    }
    for (int e = 0; e < 8; e++) {
      for (int b = 0; b < scan[255][e]; b += 128) sched1[t1++] = make_int2(e, b);
      for (int b = 0; b < scan[255][e]; b += 64)  sched2[t2++] = make_int2(e, b);
    }
    for (; t1 < MAXT1; t1++) sched1[t1] = make_int2(-1, 0);
    for (; t2 < MAXT2; t2++) sched2[t2] = make_int2(-1, 0);
  }
#pragma unroll
  for (int e = 0; e < 8; e++) scan[tid][e] -= loc[tid][e];
  __syncthreads();
#pragma unroll
  for (int i = 0; i < T_TOK / 256; i++) {
    int t = t0 + i;
    int s1 = raw[i].x, s2 = raw[i].y;
    int p1 = scan[tid][s1]++;
    idxl[s1 * T_TOK + p1] = t;
    wtl[s1 * T_TOK + p1] = __int_as_float(raw[i].z);
    int p2 = scan[tid][s2]++;
    idxl[s2 * T_TOK + p2] = t;
    wtl[s2 * T_TOK + p2] = __int_as_float(raw[i].w);
  }
}

// ---------------- GEMM1: h = gelu(x@w1) * (x@w3) * wt ------------------------
// Tile 128M x 128N x BK32, 8 waves (2Mx4N, wave = 64Mx32N). 512 threads.
// 4-buffer, stage-3-ahead, vmcnt(6) counted (tail 3->0). 1 barrier/K-step.
// LDS unit(r,u) = r*4 + (u ^ ((r>>1)&3)) -> 2-way (free) on ds_read_b128.
#define STAGE1(b, kn) do { \
    gload16(gx + (kn), &Xs[b][(wv * 64 + lane) * 8]); \
    gload16(gw1 + (kn), &W1s[b][(wv * 64 + lane) * 8]); \
    gload16(gw3 + (kn), &W3s[b][(wv * 64 + lane) * 8]); \
  } while (0)

__global__ __launch_bounds__(512, 4) void gemm1_kernel(
    const ushort_t* __restrict__ xb, const ushort_t* __restrict__ w1t,
    const ushort_t* __restrict__ w3t, const int* __restrict__ idxl,
    const float* __restrict__ wtl, const int* __restrict__ cnt,
    const int* __restrict__ offs, const int2* __restrict__ sched,
    ushort_t* __restrict__ hbuf) {
  // expert-contiguous XCD mapping: XCD x owns m-tiles [9x, 9x+9)
  int bid = blockIdx.x;
  int xcd = bid & 7, j = bid >> 3;        // j in 0..71
  int mt = xcd * 9 + (j >> 3);
  int nb = j & 7;
  int2 sc = sched[mt];
  if (sc.x < 0) return;
  int e = sc.x, base = sc.y;
  int cnte = cnt[e], off0 = offs[e];
  int rows = min(128, cnte - base);
  int n0 = nb * 128;
  __shared__ ushort_t Xs[4][4096];    // 128 rows x 32 k (8 KB/buf)
  __shared__ ushort_t W1s[4][4096];
  __shared__ ushort_t W3s[4][4096];
  __shared__ int toks[128];
  __shared__ float wtls[128];
  int tid = threadIdx.x;
  if (tid < 128) {
    int r = min(tid, rows - 1);
    toks[tid] = idxl[e * T_TOK + base + r];
    wtls[tid] = (tid < rows) ? wtl[e * T_TOK + base + tid] : 0.f;
  }
  int lane = tid & 63, wv = tid >> 6;     // wv 0..7
  int wm = (wv >> 2) * 64, wn = (wv & 3) * 32;
  __syncthreads();

  int rS = wv * 16 + (lane >> 2);
  int us = ((lane & 3) ^ ((lane >> 3) & 3)) * 8;
  const ushort_t* gx  = xb + (size_t)toks[rS] * HDIM + us;
  const ushort_t* gw1 = w1t + ((size_t)e * FDIM + n0 + rS) * HDIM + us;
  const ushort_t* gw3 = w3t + ((size_t)e * FDIM + n0 + rS) * HDIM + us;

  f32x4 accU[4][2], accV[4][2];
#pragma unroll
  for (int m = 0; m < 4; m++)
#pragma unroll
    for (int n = 0; n < 2; n++) {
      accU[m][n] = {0.f, 0.f, 0.f, 0.f};
      accV[m][n] = {0.f, 0.f, 0.f, 0.f};
    }

  STAGE1(0, 0);
  STAGE1(1, 32);
  STAGE1(2, 64);

  int uc = lane >> 4;  // 0..3
#pragma unroll
  for (int t = 0; t < 16; t++) {
    if (t < 14)       asm volatile("s_waitcnt vmcnt(6)" ::: "memory");
    else if (t == 14) asm volatile("s_waitcnt vmcnt(3)" ::: "memory");
    else              asm volatile("s_waitcnt vmcnt(0)" ::: "memory");
    __builtin_amdgcn_s_barrier();
    __builtin_amdgcn_sched_barrier(0);
    if (t < 13) STAGE1((t + 3) & 3, (t + 3) * 32);
    const int cur = t & 3;
    bf16x8 a[4], bu[2], bv[2];
#pragma unroll
    for (int m = 0; m < 4; m++) {
      int r = wm + m * 16 + (lane & 15);
      a[m] = __builtin_bit_cast(bf16x8,
          *reinterpret_cast<const uint4*>(&Xs[cur][(r * 4 + (uc ^ ((r >> 1) & 3))) * 8]));
    }
#pragma unroll
    for (int n = 0; n < 2; n++) {
      int r = wn + n * 16 + (lane & 15);
      bu[n] = __builtin_bit_cast(bf16x8,
          *reinterpret_cast<const uint4*>(&W1s[cur][(r * 4 + (uc ^ ((r >> 1) & 3))) * 8]));
      bv[n] = __builtin_bit_cast(bf16x8,
          *reinterpret_cast<const uint4*>(&W3s[cur][(r * 4 + (uc ^ ((r >> 1) & 3))) * 8]));
    }
#pragma unroll
    for (int m = 0; m < 4; m++)
#pragma unroll
      for (int n = 0; n < 2; n++) {
        accU[m][n] = __builtin_amdgcn_mfma_f32_16x16x32_bf16(a[m], bu[n], accU[m][n], 0, 0, 0);
        accV[m][n] = __builtin_amdgcn_mfma_f32_16x16x32_bf16(a[m], bv[n], accV[m][n], 0, 0, 0);
      }
  }

#pragma unroll
  for (int m = 0; m < 4; m++) {
#pragma unroll
    for (int rr = 0; rr < 4; rr++) {
      int row = wm + m * 16 + ((lane >> 4) << 2) + rr;
      if (row < rows) {
        float wgt = wtls[row];
        size_t po = (size_t)(off0 + base + row) * FDIM + n0 + wn + (lane & 15);
#pragma unroll
        for (int n = 0; n < 2; n++) {
          float u = accU[m][n][rr], v = accV[m][n][rr];
          float h = 0.5f * u * (1.0f + erff(u * 0.707106781186547524f)) * v * wgt;
          hbuf[po + n * 16] = (ushort_t)f2bf(h);
        }
      }
    }
  }
}

// ---------------- GEMM2: out[tok] += h @ w2  (contiguous slots) --------------
// Tile 64M x 128N x BK32, 4 waves (2Mx2N, wave = 32Mx64N). 48 KB LDS -> 3 blk/CU.
// 4-buffer, stage-3-ahead, vmcnt(6) counted (tail 3->0). fp32 atomicAdd epilogue
// (2 commutative contributions per element -> deterministic).
#define STAGE2(b, kn) do { \
    gload16(ga + (kn), &As[b][(wv * 64 + lane) * 8]); \
    gload16(gb0 + (kn), &Bs[b][(wv * 128 + lane) * 8]); \
    gload16(gb1 + (kn), &Bs[b][(wv * 128 + 64 + lane) * 8]); \
  } while (0)

__global__ __launch_bounds__(256, 3) void gemm2_kernel(
    const ushort_t* __restrict__ hbuf, const ushort_t* __restrict__ w2t,
    const int* __restrict__ idxl, const int* __restrict__ cnt,
    const int* __restrict__ offs, const int2* __restrict__ sched,
    float* __restrict__ out) {
  // expert-contiguous XCD mapping: XCD x owns m-tiles [17x, 17x+17)
  int bid = blockIdx.x;
  int xcd = bid & 7, j = bid >> 3;        // j in 0..67
  int mt = xcd * 17 + (j >> 2);
  int nb = j & 3;
  int2 sc = sched[mt];
  if (sc.x < 0) return;
  int e = sc.x, base = sc.y;
  int cnte = cnt[e], off0 = offs[e];
  int rows = min(64, cnte - base);
  int n0 = nb * 128;
  __shared__ ushort_t As[4][2048];   // 64 rows x 32 k (4 KB/buf)
  __shared__ ushort_t Bs[4][4096];   // 128 n-rows x 32 k (8 KB/buf)
  __shared__ int toks[64];
  int tid = threadIdx.x;
  if (tid < 64) toks[tid] = idxl[e * T_TOK + base + min(tid, rows - 1)];
  int lane = tid & 63, wv = tid >> 6;
  int wm = (wv >> 1) * 32, wn = (wv & 1) * 64;
  __syncthreads();

  int rA = wv * 16 + (lane >> 2);
  int rB = wv * 32 + (lane >> 2);
  int us = ((lane & 3) ^ ((lane >> 3) & 3)) * 8;
  const ushort_t* ga = hbuf + (size_t)(off0 + base + min(rA, rows - 1)) * FDIM + us;
  const ushort_t* gb0 = w2t + ((size_t)e * HDIM + n0 + rB) * FDIM + us;
  const ushort_t* gb1 = w2t + ((size_t)e * HDIM + n0 + rB + 16) * FDIM + us;

  f32x4 acc[2][4];
#pragma unroll
  for (int m = 0; m < 2; m++)
#pragma unroll
    for (int n = 0; n < 4; n++) acc[m][n] = {0.f, 0.f, 0.f, 0.f};

  STAGE2(0, 0);
  STAGE2(1, 32);
  STAGE2(2, 64);

  int uc = lane >> 4;
#pragma unroll
  for (int t = 0; t < 32; t++) {
    if (t < 30)       asm volatile("s_waitcnt vmcnt(6)" ::: "memory");
    else if (t == 30) asm volatile("s_waitcnt vmcnt(3)" ::: "memory");
    else              asm volatile("s_waitcnt vmcnt(0)" ::: "memory");
    __builtin_amdgcn_s_barrier();
    __builtin_amdgcn_sched_barrier(0);
    if (t < 29) STAGE2((t + 3) & 3, (t + 3) * 32);
    const int cur = t & 3;
    bf16x8 a[2], b[4];
#pragma unroll
    for (int m = 0; m < 2; m++) {
      int r = wm + m * 16 + (lane & 15);
      a[m] = __builtin_bit_cast(bf16x8,
          *reinterpret_cast<const uint4*>(&As[cur][(r * 4 + (uc ^ ((r >> 1) & 3))) * 8]));
    }
#pragma unroll
    for (int n = 0; n < 4; n++) {
      int r = wn + n * 16 + (lane & 15);
      b[n] = __builtin_bit_cast(bf16x8,
          *reinterpret_cast<const uint4*>(&Bs[cur][(r * 4 + (uc ^ ((r >> 1) & 3))) * 8]));
    }
#pragma unroll
    for (int m = 0; m < 2; m++)
#pragma unroll
      for (int n = 0; n < 4; n++)
        acc[m][n] = __builtin_amdgcn_mfma_f32_16x16x32_bf16(a[m], b[n], acc[m][n], 0, 0, 0);
  }

#pragma unroll
  for (int m = 0; m < 2; m++) {
#pragma unroll
    for (int rr = 0; rr < 4; rr++) {
      int row = wm + m * 16 + ((lane >> 4) << 2) + rr;
      if (row < rows) {
        int tok = toks[row];
        float* po = out + (size_t)tok * HDIM + n0 + wn + (lane & 15);
#pragma unroll
        for (int n = 0; n < 4; n++) atomicAdd(po + n * 16, acc[m][n][rr]);
      }
    }
  }
}

// ---------------- launch ----------------------------------------------------
extern "C" void kernel_launch(void* const* d_in, const int* in_sizes, int n_in,
                              void* d_out, int out_size, void* d_ws, size_t ws_size,
                              hipStream_t stream) {
  const float* x  = (const float*)d_in[0];
  const float* wg = (const float*)d_in[1];
  const float* bg = (const float*)d_in[2];
  const float* w1 = (const float*)d_in[3];
  const float* w3 = (const float*)d_in[4];
  const float* w2 = (const float*)d_in[5];
  float* out = (float*)d_out;
  char* ws = (char*)d_ws;

  int*   cnt    = (int*)(ws + 0);
  int*   offs   = (int*)(ws + 64);
  int2*  sched1 = (int2*)(ws + 128);                 // 576 B
  int2*  sched2 = (int2*)(ws + 1024);                // 1088 B
  int4*  selraw = (int4*)(ws + 65536);               // 64 KB
  int*   idxl   = (int*)(ws + 131072);               // 128 KB
  float* wtl    = (float*)(ws + 262144);             // 128 KB
  ushort_t* xb   = (ushort_t*)(ws + (1ull << 20));   // 4 MB
  ushort_t* w1t  = (ushort_t*)(ws + (5ull << 20));   // 8 MB
  ushort_t* w3t  = (ushort_t*)(ws + (13ull << 20));  // 8 MB
  ushort_t* w2t  = (ushort_t*)(ws + (21ull << 20));  // 8 MB
  ushort_t* hbuf = (ushort_t*)(ws + (29ull << 20));  // 16 MB

  hipMemsetAsync(out, 0, (size_t)out_size * sizeof(float), stream);
  pre_kernel<<<1024 + 12288, 256, 0, stream>>>(x, wg, bg, selraw, xb,
                                               w1, w3, w2, w1t, w3t, w2t);
  build_kernel<<<1, 256, 0, stream>>>(selraw, cnt, offs, sched1, sched2, idxl, wtl);
  gemm1_kernel<<<8 * MAXT1, 512, 0, stream>>>(xb, w1t, w3t, idxl, wtl, cnt,
                                              offs, sched1, hbuf);
  gemm2_kernel<<<4 * MAXT2, 256, 0, stream>>>(hbuf, w2t, idxl, cnt, offs,
                                              sched2, out);
}

// Round 11
// 111.769 us; speedup vs baseline: 1.1369x; 1.1369x over previous
//
#include <hip/hip_runtime.h>
#include <hip/hip_bf16.h>

// GRIN MoE feed-forward, routed top-2, bf16 MFMA grouped GEMM.
// T=4096 tokens, H=512, F=1024, E=8.
// R1: atomic-free routing (counting sort), fused x->bf16 into gating.
// R2: gload_lds(16B, pre-swizzled source).
// R3: counted-vmcnt 3-buffer pipeline, 2-way swizzle, gemm2+combine fusion.
// R7: fused gating+transconv launch.
// R9: expert-contiguous XCD mapping (best: 117us; gemm1 40.5us, FETCH=compulsory).
// R10 (4-buffer) regressed -> reverted.
// R11: gemm2 rebuilt as exact clone of gemm1's proven 8-wave 128x128 BK32
//      3-buffer pipeline (48KB LDS -> 3 blk/CU, 32 steps, 1.5x intensity);
//      shares the 128-granular schedule.

#define T_TOK 4096
#define HDIM  512
#define FDIM  1024
#define NEXP  8
#define MAXT1 72     // 128-granular M tiles

typedef __attribute__((ext_vector_type(8))) __bf16 bf16x8;
typedef __attribute__((ext_vector_type(4))) float  f32x4;
typedef unsigned short ushort_t;

__device__ __forceinline__ unsigned int f2bf(float f) {
  __hip_bfloat16 h = __float2bfloat16(f);
  return (unsigned int)__builtin_bit_cast(unsigned short, h);
}

// global -> LDS direct copy, 16B per lane (wave writes 64 consecutive 16B units)
__device__ __forceinline__ void gload16(const ushort_t* g, ushort_t* l) {
  __builtin_amdgcn_global_load_lds(
      (const __attribute__((address_space(1))) unsigned int*)g,
      (__attribute__((address_space(3))) unsigned int*)l, 16, 0, 0);
}

// ------- fused pre: gating (blocks 0..1023) + weight transconv (rest) --------
__global__ void pre_kernel(const float* __restrict__ x, const float* __restrict__ wg,
                           const float* __restrict__ bg, int4* __restrict__ selraw,
                           ushort_t* __restrict__ xbuf,
                           const float* __restrict__ w1, const float* __restrict__ w3,
                           const float* __restrict__ w2, ushort_t* __restrict__ w1t,
                           ushort_t* __restrict__ w3t, ushort_t* __restrict__ w2t) {
  __shared__ float tile[32][33];
  int blk = blockIdx.x;
  if (blk < 1024) {
    int wv = threadIdx.x >> 6;
    int lane = threadIdx.x & 63;
    int t = blk * 4 + wv;
    const float* xr = x + (size_t)t * HDIM + lane * 8;
    float4 xa = *reinterpret_cast<const float4*>(xr);
    float4 xb = *reinterpret_cast<const float4*>(xr + 4);
    uint4 o;
    o.x = f2bf(xa.x) | (f2bf(xa.y) << 16);
    o.y = f2bf(xa.z) | (f2bf(xa.w) << 16);
    o.z = f2bf(xb.x) | (f2bf(xb.y) << 16);
    o.w = f2bf(xb.z) | (f2bf(xb.w) << 16);
    *reinterpret_cast<uint4*>(xbuf + (size_t)t * HDIM + lane * 8) = o;

    float xv[8] = {xa.x, xa.y, xa.z, xa.w, xb.x, xb.y, xb.z, xb.w};
    float acc[8];
#pragma unroll
    for (int e = 0; e < 8; e++) acc[e] = 0.f;
    int h0 = lane * 8;
#pragma unroll
    for (int j = 0; j < 8; j++) {
      const float4* wr = reinterpret_cast<const float4*>(wg + (size_t)(h0 + j) * 8);
      float4 w0 = wr[0], w1v = wr[1];
      float xj = xv[j];
      acc[0] += xj * w0.x; acc[1] += xj * w0.y; acc[2] += xj * w0.z; acc[3] += xj * w0.w;
      acc[4] += xj * w1v.x; acc[5] += xj * w1v.y; acc[6] += xj * w1v.z; acc[7] += xj * w1v.w;
    }
#pragma unroll
    for (int s = 32; s >= 1; s >>= 1) {
#pragma unroll
      for (int e = 0; e < 8; e++) acc[e] += __shfl_xor(acc[e], s, 64);
    }
    if (lane == 0) {
      float sc[8];
      float mx = -1e30f;
      for (int e = 0; e < 8; e++) { sc[e] = acc[e] + bg[e]; mx = fmaxf(mx, sc[e]); }
      float sum = 0.f;
      for (int e = 0; e < 8; e++) { sc[e] = expf(sc[e] - mx); sum += sc[e]; }
      for (int e = 0; e < 8; e++) sc[e] /= sum;
      int s1 = 0; float mx1 = sc[0];
      for (int e = 1; e < 8; e++) if (sc[e] > mx1) { mx1 = sc[e]; s1 = e; }
      float den1 = 0.f;
      for (int e = 0; e < 8; e++)
        if (!((mx1 - sc[e]) / mx1 > 0.02f)) den1 += expf(sc[e] - mx1);
      float mult1 = 1.0f / den1;
      int s2 = 0; float mx2 = -1e30f;
      for (int e = 0; e < 8; e++) if (e != s1 && sc[e] > mx2) { mx2 = sc[e]; s2 = e; }
      float den2 = 0.f;
      for (int e = 0; e < 8; e++) {
        if (e == s1) continue;
        float fac = fmaxf(sc[e], mx2);
        if (!((mx2 - sc[e]) / fac > 0.02f)) den2 += expf(sc[e] - mx2);
      }
      float mult2 = 1.0f / den2;
      selraw[t] = make_int4(s1, s2, __float_as_int(mult1), __float_as_int(mult2));
    }
    return;
  }
  int b = blk - 1024;
  const float* src; ushort_t* dst; int R, C, rt, ct, e;
  if (b < 8192) {
    src = (b < 4096) ? w1 : w3; dst = (b < 4096) ? w1t : w3t;
    int r = b & 4095; e = r >> 9; r &= 511;
    R = HDIM; C = FDIM; rt = r >> 5; ct = r & 31;
  } else {
    src = w2; dst = w2t;
    int r = b - 8192; e = r >> 9; r &= 511;
    R = FDIM; C = HDIM; rt = r >> 4; ct = r & 15;
  }
  int rb = rt * 32, cb = ct * 32;
  int tr = threadIdx.x >> 3, tc = (threadIdx.x & 7) * 4;
  const float* s = src + ((size_t)e * R + rb + tr) * C + cb + tc;
  float4 v = *reinterpret_cast<const float4*>(s);
  tile[tc + 0][tr] = v.x; tile[tc + 1][tr] = v.y;
  tile[tc + 2][tr] = v.z; tile[tc + 3][tr] = v.w;
  __syncthreads();
  ushort4 ov = {(ushort_t)f2bf(tile[tr][tc]), (ushort_t)f2bf(tile[tr][tc + 1]),
                (ushort_t)f2bf(tile[tr][tc + 2]), (ushort_t)f2bf(tile[tr][tc + 3])};
  *reinterpret_cast<ushort4*>(dst + ((size_t)e * C + cb + tr) * R + rb + tc) = ov;
}

// ------- build: stable counting sort into per-expert lists + schedule --------
__global__ __launch_bounds__(256) void build_kernel(
    const int4* __restrict__ selraw, int* __restrict__ cnt, int* __restrict__ offs,
    int2* __restrict__ sched1, int* __restrict__ idxl, float* __restrict__ wtl) {
  __shared__ int scan[256][8];
  __shared__ int loc[256][8];
  int tid = threadIdx.x;
#pragma unroll
  for (int e = 0; e < 8; e++) { scan[tid][e] = 0; loc[tid][e] = 0; }
  int t0 = tid * (T_TOK / 256);
  int4 raw[T_TOK / 256];
#pragma unroll
  for (int i = 0; i < T_TOK / 256; i++) {
    raw[i] = selraw[t0 + i];
    loc[tid][raw[i].x]++;
    loc[tid][raw[i].y]++;
  }
#pragma unroll
  for (int e = 0; e < 8; e++) scan[tid][e] = loc[tid][e];
  __syncthreads();
  for (int s = 1; s < 256; s <<= 1) {
    int v[8];
    if (tid >= s) {
#pragma unroll
      for (int e = 0; e < 8; e++) v[e] = scan[tid - s][e];
    }
    __syncthreads();
    if (tid >= s) {
#pragma unroll
      for (int e = 0; e < 8; e++) scan[tid][e] += v[e];
    }
    __syncthreads();
  }
  if (tid == 0) {
    int a = 0, t1 = 0;
    for (int e = 0; e < 8; e++) {
      int ce = scan[255][e];
      cnt[e] = ce; offs[e] = a; a += ce;
    }
    for (int e = 0; e < 8; e++)
      for (int b = 0; b < scan[255][e]; b += 128) sched1[t1++] = make_int2(e, b);
    for (; t1 < MAXT1; t1++) sched1[t1] = make_int2(-1, 0);
  }
#pragma unroll
  for (int e = 0; e < 8; e++) scan[tid][e] -= loc[tid][e];
  __syncthreads();
#pragma unroll
  for (int i = 0; i < T_TOK / 256; i++) {
    int t = t0 + i;
    int s1 = raw[i].x, s2 = raw[i].y;
    int p1 = scan[tid][s1]++;
    idxl[s1 * T_TOK + p1] = t;
    wtl[s1 * T_TOK + p1] = __int_as_float(raw[i].z);
    int p2 = scan[tid][s2]++;
    idxl[s2 * T_TOK + p2] = t;
    wtl[s2 * T_TOK + p2] = __int_as_float(raw[i].w);
  }
}

// ---------------- GEMM1: h = gelu(x@w1) * (x@w3) * wt ------------------------
// Tile 128M x 128N x BK32, 8 waves (2Mx4N, wave = 64Mx32N). 512 threads.
// 3-buffer counted-vmcnt pipeline: 3 gload16/wave/stage, vmcnt(3) in-loop.
// LDS unit(r,u) = r*4 + (u ^ ((r>>1)&3)) -> 2-way (free) on ds_read_b128.
#define STAGE1(b, kn) do { \
    gload16(gx + (kn), &Xs[b][(wv * 64 + lane) * 8]); \
    gload16(gw1 + (kn), &W1s[b][(wv * 64 + lane) * 8]); \
    gload16(gw3 + (kn), &W3s[b][(wv * 64 + lane) * 8]); \
  } while (0)

__global__ __launch_bounds__(512, 4) void gemm1_kernel(
    const ushort_t* __restrict__ xb, const ushort_t* __restrict__ w1t,
    const ushort_t* __restrict__ w3t, const int* __restrict__ idxl,
    const float* __restrict__ wtl, const int* __restrict__ cnt,
    const int* __restrict__ offs, const int2* __restrict__ sched,
    ushort_t* __restrict__ hbuf) {
  // expert-contiguous XCD mapping: XCD x owns m-tiles [9x, 9x+9)
  int bid = blockIdx.x;
  int xcd = bid & 7, j = bid >> 3;        // j in 0..71
  int mt = xcd * 9 + (j >> 3);
  int nb = j & 7;
  int2 sc = sched[mt];
  if (sc.x < 0) return;
  int e = sc.x, base = sc.y;
  int cnte = cnt[e], off0 = offs[e];
  int rows = min(128, cnte - base);
  int n0 = nb * 128;
  __shared__ ushort_t Xs[3][4096];    // 128 rows x 32 k (8 KB/buf)
  __shared__ ushort_t W1s[3][4096];
  __shared__ ushort_t W3s[3][4096];
  __shared__ int toks[128];
  __shared__ float wtls[128];
  int tid = threadIdx.x;
  if (tid < 128) {
    int r = min(tid, rows - 1);
    toks[tid] = idxl[e * T_TOK + base + r];
    wtls[tid] = (tid < rows) ? wtl[e * T_TOK + base + tid] : 0.f;
  }
  int lane = tid & 63, wv = tid >> 6;     // wv 0..7
  int wm = (wv >> 2) * 64, wn = (wv & 3) * 32;
  __syncthreads();

  int rS = wv * 16 + (lane >> 2);
  int us = ((lane & 3) ^ ((lane >> 3) & 3)) * 8;
  const ushort_t* gx  = xb + (size_t)toks[rS] * HDIM + us;
  const ushort_t* gw1 = w1t + ((size_t)e * FDIM + n0 + rS) * HDIM + us;
  const ushort_t* gw3 = w3t + ((size_t)e * FDIM + n0 + rS) * HDIM + us;

  f32x4 accU[4][2], accV[4][2];
#pragma unroll
  for (int m = 0; m < 4; m++)
#pragma unroll
    for (int n = 0; n < 2; n++) {
      accU[m][n] = {0.f, 0.f, 0.f, 0.f};
      accV[m][n] = {0.f, 0.f, 0.f, 0.f};
    }

  STAGE1(0, 0);
  STAGE1(1, 32);

  int uc = lane >> 4;  // 0..3
#pragma unroll
  for (int t = 0; t < 16; t++) {
    if (t < 15) asm volatile("s_waitcnt vmcnt(3)" ::: "memory");
    else        asm volatile("s_waitcnt vmcnt(0)" ::: "memory");
    __builtin_amdgcn_s_barrier();
    __builtin_amdgcn_sched_barrier(0);
    if (t < 14) STAGE1((t + 2) % 3, (t + 2) * 32);
    const int cur = t % 3;
    bf16x8 a[4], bu[2], bv[2];
#pragma unroll
    for (int m = 0; m < 4; m++) {
      int r = wm + m * 16 + (lane & 15);
      a[m] = __builtin_bit_cast(bf16x8,
          *reinterpret_cast<const uint4*>(&Xs[cur][(r * 4 + (uc ^ ((r >> 1) & 3))) * 8]));
    }
#pragma unroll
    for (int n = 0; n < 2; n++) {
      int r = wn + n * 16 + (lane & 15);
      bu[n] = __builtin_bit_cast(bf16x8,
          *reinterpret_cast<const uint4*>(&W1s[cur][(r * 4 + (uc ^ ((r >> 1) & 3))) * 8]));
      bv[n] = __builtin_bit_cast(bf16x8,
          *reinterpret_cast<const uint4*>(&W3s[cur][(r * 4 + (uc ^ ((r >> 1) & 3))) * 8]));
    }
#pragma unroll
    for (int m = 0; m < 4; m++)
#pragma unroll
      for (int n = 0; n < 2; n++) {
        accU[m][n] = __builtin_amdgcn_mfma_f32_16x16x32_bf16(a[m], bu[n], accU[m][n], 0, 0, 0);
        accV[m][n] = __builtin_amdgcn_mfma_f32_16x16x32_bf16(a[m], bv[n], accV[m][n], 0, 0, 0);
      }
  }

#pragma unroll
  for (int m = 0; m < 4; m++) {
#pragma unroll
    for (int rr = 0; rr < 4; rr++) {
      int row = wm + m * 16 + ((lane >> 4) << 2) + rr;
      if (row < rows) {
        float wgt = wtls[row];
        size_t po = (size_t)(off0 + base + row) * FDIM + n0 + wn + (lane & 15);
#pragma unroll
        for (int n = 0; n < 2; n++) {
          float u = accU[m][n][rr], v = accV[m][n][rr];
          float h = 0.5f * u * (1.0f + erff(u * 0.707106781186547524f)) * v * wgt;
          hbuf[po + n * 16] = (ushort_t)f2bf(h);
        }
      }
    }
  }
}

// ---------------- GEMM2: out[tok] += h @ w2  (contiguous slots) --------------
// Clone of gemm1's structure: 128M x 128N x BK32, 8 waves (2Mx4N), 512 threads,
// 3-buffer counted-vmcnt pipeline (2 gload16/wave/stage, vmcnt(2)), 32 K-steps.
// 48 KB LDS -> 3 blocks/CU. fp32 atomicAdd epilogue (2 commutative
// contributions per element -> deterministic).
#define STAGE2(b, kn) do { \
    gload16(ga + (kn), &As[b][(wv * 64 + lane) * 8]); \
    gload16(gb + (kn), &Bs[b][(wv * 64 + lane) * 8]); \
  } while (0)

__global__ __launch_bounds__(512, 4) void gemm2_kernel(
    const ushort_t* __restrict__ hbuf, const ushort_t* __restrict__ w2t,
    const int* __restrict__ idxl, const int* __restrict__ cnt,
    const int* __restrict__ offs, const int2* __restrict__ sched,
    float* __restrict__ out) {
  // expert-contiguous XCD mapping: XCD x owns m-tiles [9x, 9x+9); 4 n-blocks
  int bid = blockIdx.x;
  int xcd = bid & 7, j = bid >> 3;        // j in 0..35
  int mt = xcd * 9 + (j >> 2);
  int nb = j & 3;
  int2 sc = sched[mt];
  if (sc.x < 0) return;
  int e = sc.x, base = sc.y;
  int cnte = cnt[e], off0 = offs[e];
  int rows = min(128, cnte - base);
  int n0 = nb * 128;
  __shared__ ushort_t As[3][4096];   // 128 rows x 32 k (8 KB/buf)
  __shared__ ushort_t Bs[3][4096];   // 128 n-rows x 32 k
  __shared__ int toks[128];
  int tid = threadIdx.x;
  if (tid < 128) toks[tid] = idxl[e * T_TOK + base + min(tid, rows - 1)];
  int lane = tid & 63, wv = tid >> 6;     // wv 0..7
  int wm = (wv >> 2) * 64, wn = (wv & 3) * 32;
  __syncthreads();

  int rS = wv * 16 + (lane >> 2);
  int us = ((lane & 3) ^ ((lane >> 3) & 3)) * 8;
  const ushort_t* ga = hbuf + (size_t)(off0 + base + min(rS, rows - 1)) * FDIM + us;
  const ushort_t* gb = w2t + ((size_t)e * HDIM + n0 + rS) * FDIM + us;

  f32x4 acc[4][2];
#pragma unroll
  for (int m = 0; m < 4; m++)
#pragma unroll
    for (int n = 0; n < 2; n++) acc[m][n] = {0.f, 0.f, 0.f, 0.f};

  STAGE2(0, 0);
  STAGE2(1, 32);

  int uc = lane >> 4;  // 0..3
#pragma unroll
  for (int t = 0; t < 32; t++) {
    if (t < 31) asm volatile("s_waitcnt vmcnt(2)" ::: "memory");
    else        asm volatile("s_waitcnt vmcnt(0)" ::: "memory");
    __builtin_amdgcn_s_barrier();
    __builtin_amdgcn_sched_barrier(0);
    if (t < 30) STAGE2((t + 2) % 3, (t + 2) * 32);
    const int cur = t % 3;
    bf16x8 a[4], b[2];
#pragma unroll
    for (int m = 0; m < 4; m++) {
      int r = wm + m * 16 + (lane & 15);
      a[m] = __builtin_bit_cast(bf16x8,
          *reinterpret_cast<const uint4*>(&As[cur][(r * 4 + (uc ^ ((r >> 1) & 3))) * 8]));
    }
#pragma unroll
    for (int n = 0; n < 2; n++) {
      int r = wn + n * 16 + (lane & 15);
      b[n] = __builtin_bit_cast(bf16x8,
          *reinterpret_cast<const uint4*>(&Bs[cur][(r * 4 + (uc ^ ((r >> 1) & 3))) * 8]));
    }
#pragma unroll
    for (int m = 0; m < 4; m++)
#pragma unroll
      for (int n = 0; n < 2; n++)
        acc[m][n] = __builtin_amdgcn_mfma_f32_16x16x32_bf16(a[m], b[n], acc[m][n], 0, 0, 0);
  }

#pragma unroll
  for (int m = 0; m < 4; m++) {
#pragma unroll
    for (int rr = 0; rr < 4; rr++) {
      int row = wm + m * 16 + ((lane >> 4) << 2) + rr;
      if (row < rows) {
        int tok = toks[row];
        float* po = out + (size_t)tok * HDIM + n0 + wn + (lane & 15);
#pragma unroll
        for (int n = 0; n < 2; n++) atomicAdd(po + n * 16, acc[m][n][rr]);
      }
    }
  }
}

// ---------------- launch ----------------------------------------------------
extern "C" void kernel_launch(void* const* d_in, const int* in_sizes, int n_in,
                              void* d_out, int out_size, void* d_ws, size_t ws_size,
                              hipStream_t stream) {
  const float* x  = (const float*)d_in[0];
  const float* wg = (const float*)d_in[1];
  const float* bg = (const float*)d_in[2];
  const float* w1 = (const float*)d_in[3];
  const float* w3 = (const float*)d_in[4];
  const float* w2 = (const float*)d_in[5];
  float* out = (float*)d_out;
  char* ws = (char*)d_ws;

  int*   cnt    = (int*)(ws + 0);
  int*   offs   = (int*)(ws + 64);
  int2*  sched1 = (int2*)(ws + 128);                 // 576 B
  int4*  selraw = (int4*)(ws + 65536);               // 64 KB
  int*   idxl   = (int*)(ws + 131072);               // 128 KB
  float* wtl    = (float*)(ws + 262144);             // 128 KB
  ushort_t* xb   = (ushort_t*)(ws + (1ull << 20));   // 4 MB
  ushort_t* w1t  = (ushort_t*)(ws + (5ull << 20));   // 8 MB
  ushort_t* w3t  = (ushort_t*)(ws + (13ull << 20));  // 8 MB
  ushort_t* w2t  = (ushort_t*)(ws + (21ull << 20));  // 8 MB
  ushort_t* hbuf = (ushort_t*)(ws + (29ull << 20));  // 16 MB

  hipMemsetAsync(out, 0, (size_t)out_size * sizeof(float), stream);
  pre_kernel<<<1024 + 12288, 256, 0, stream>>>(x, wg, bg, selraw, xb,
                                               w1, w3, w2, w1t, w3t, w2t);
  build_kernel<<<1, 256, 0, stream>>>(selraw, cnt, offs, sched1, idxl, wtl);
  gemm1_kernel<<<8 * MAXT1, 512, 0, stream>>>(xb, w1t, w3t, idxl, wtl, cnt,
                                              offs, sched1, hbuf);
  gemm2_kernel<<<8 * 36, 512, 0, stream>>>(hbuf, w2t, idxl, cnt, offs,
                                           sched1, out);
}

// Round 12
// 107.224 us; speedup vs baseline: 1.1851x; 1.0424x over previous
//
#include <hip/hip_runtime.h>
#include <hip/hip_bf16.h>

// GRIN MoE feed-forward, routed top-2, bf16 MFMA grouped GEMM.
// T=4096 tokens, H=512, F=1024, E=8.
// R1: atomic-free routing (counting sort), fused x->bf16 into gating.
// R2: gload_lds(16B, pre-swizzled source).
// R3: counted-vmcnt 3-buffer pipeline, 2-way swizzle, gemm2+combine fusion.
// R7: fused gating+transconv launch.
// R9: expert-contiguous XCD mapping.
// R11: gemm2 = clone of gemm1's 8-wave 128x128 BK32 pipeline (111.8us).
// R12: kill the 41us hipMemsetAsync(out) (runtime fill kernel @205GB/s, 9% occ)
//      -> zero `out` with 2048 extra blocks inside pre_kernel.

#define T_TOK 4096
#define HDIM  512
#define FDIM  1024
#define NEXP  8
#define MAXT1 72     // 128-granular M tiles

typedef __attribute__((ext_vector_type(8))) __bf16 bf16x8;
typedef __attribute__((ext_vector_type(4))) float  f32x4;
typedef unsigned short ushort_t;

__device__ __forceinline__ unsigned int f2bf(float f) {
  __hip_bfloat16 h = __float2bfloat16(f);
  return (unsigned int)__builtin_bit_cast(unsigned short, h);
}

// global -> LDS direct copy, 16B per lane (wave writes 64 consecutive 16B units)
__device__ __forceinline__ void gload16(const ushort_t* g, ushort_t* l) {
  __builtin_amdgcn_global_load_lds(
      (const __attribute__((address_space(1))) unsigned int*)g,
      (__attribute__((address_space(3))) unsigned int*)l, 16, 0, 0);
}

// --- fused pre: gating (0..1023) + transconv (1024..13311) + zero-out (rest) --
__global__ void pre_kernel(const float* __restrict__ x, const float* __restrict__ wg,
                           const float* __restrict__ bg, int4* __restrict__ selraw,
                           ushort_t* __restrict__ xbuf,
                           const float* __restrict__ w1, const float* __restrict__ w3,
                           const float* __restrict__ w2, ushort_t* __restrict__ w1t,
                           ushort_t* __restrict__ w3t, ushort_t* __restrict__ w2t,
                           float* __restrict__ outz) {
  __shared__ float tile[32][33];
  int blk = blockIdx.x;
  if (blk >= 13312) {
    // zero 4 KB of out per block: 2048 blocks x 256 thr x float4 = 8 MB
    int i = (blk - 13312) * 1024 + threadIdx.x * 4;
    *reinterpret_cast<float4*>(outz + i) = make_float4(0.f, 0.f, 0.f, 0.f);
    return;
  }
  if (blk < 1024) {
    int wv = threadIdx.x >> 6;
    int lane = threadIdx.x & 63;
    int t = blk * 4 + wv;
    const float* xr = x + (size_t)t * HDIM + lane * 8;
    float4 xa = *reinterpret_cast<const float4*>(xr);
    float4 xb = *reinterpret_cast<const float4*>(xr + 4);
    uint4 o;
    o.x = f2bf(xa.x) | (f2bf(xa.y) << 16);
    o.y = f2bf(xa.z) | (f2bf(xa.w) << 16);
    o.z = f2bf(xb.x) | (f2bf(xb.y) << 16);
    o.w = f2bf(xb.z) | (f2bf(xb.w) << 16);
    *reinterpret_cast<uint4*>(xbuf + (size_t)t * HDIM + lane * 8) = o;

    float xv[8] = {xa.x, xa.y, xa.z, xa.w, xb.x, xb.y, xb.z, xb.w};
    float acc[8];
#pragma unroll
    for (int e = 0; e < 8; e++) acc[e] = 0.f;
    int h0 = lane * 8;
#pragma unroll
    for (int j = 0; j < 8; j++) {
      const float4* wr = reinterpret_cast<const float4*>(wg + (size_t)(h0 + j) * 8);
      float4 w0 = wr[0], w1v = wr[1];
      float xj = xv[j];
      acc[0] += xj * w0.x; acc[1] += xj * w0.y; acc[2] += xj * w0.z; acc[3] += xj * w0.w;
      acc[4] += xj * w1v.x; acc[5] += xj * w1v.y; acc[6] += xj * w1v.z; acc[7] += xj * w1v.w;
    }
#pragma unroll
    for (int s = 32; s >= 1; s >>= 1) {
#pragma unroll
      for (int e = 0; e < 8; e++) acc[e] += __shfl_xor(acc[e], s, 64);
    }
    if (lane == 0) {
      float sc[8];
      float mx = -1e30f;
      for (int e = 0; e < 8; e++) { sc[e] = acc[e] + bg[e]; mx = fmaxf(mx, sc[e]); }
      float sum = 0.f;
      for (int e = 0; e < 8; e++) { sc[e] = expf(sc[e] - mx); sum += sc[e]; }
      for (int e = 0; e < 8; e++) sc[e] /= sum;
      int s1 = 0; float mx1 = sc[0];
      for (int e = 1; e < 8; e++) if (sc[e] > mx1) { mx1 = sc[e]; s1 = e; }
      float den1 = 0.f;
      for (int e = 0; e < 8; e++)
        if (!((mx1 - sc[e]) / mx1 > 0.02f)) den1 += expf(sc[e] - mx1);
      float mult1 = 1.0f / den1;
      int s2 = 0; float mx2 = -1e30f;
      for (int e = 0; e < 8; e++) if (e != s1 && sc[e] > mx2) { mx2 = sc[e]; s2 = e; }
      float den2 = 0.f;
      for (int e = 0; e < 8; e++) {
        if (e == s1) continue;
        float fac = fmaxf(sc[e], mx2);
        if (!((mx2 - sc[e]) / fac > 0.02f)) den2 += expf(sc[e] - mx2);
      }
      float mult2 = 1.0f / den2;
      selraw[t] = make_int4(s1, s2, __float_as_int(mult1), __float_as_int(mult2));
    }
    return;
  }
  int b = blk - 1024;
  const float* src; ushort_t* dst; int R, C, rt, ct, e;
  if (b < 8192) {
    src = (b < 4096) ? w1 : w3; dst = (b < 4096) ? w1t : w3t;
    int r = b & 4095; e = r >> 9; r &= 511;
    R = HDIM; C = FDIM; rt = r >> 5; ct = r & 31;
  } else {
    src = w2; dst = w2t;
    int r = b - 8192; e = r >> 9; r &= 511;
    R = FDIM; C = HDIM; rt = r >> 4; ct = r & 15;
  }
  int rb = rt * 32, cb = ct * 32;
  int tr = threadIdx.x >> 3, tc = (threadIdx.x & 7) * 4;
  const float* s = src + ((size_t)e * R + rb + tr) * C + cb + tc;
  float4 v = *reinterpret_cast<const float4*>(s);
  tile[tc + 0][tr] = v.x; tile[tc + 1][tr] = v.y;
  tile[tc + 2][tr] = v.z; tile[tc + 3][tr] = v.w;
  __syncthreads();
  ushort4 ov = {(ushort_t)f2bf(tile[tr][tc]), (ushort_t)f2bf(tile[tr][tc + 1]),
                (ushort_t)f2bf(tile[tr][tc + 2]), (ushort_t)f2bf(tile[tr][tc + 3])};
  *reinterpret_cast<ushort4*>(dst + ((size_t)e * C + cb + tr) * R + rb + tc) = ov;
}

// ------- build: stable counting sort into per-expert lists + schedule --------
__global__ __launch_bounds__(256) void build_kernel(
    const int4* __restrict__ selraw, int* __restrict__ cnt, int* __restrict__ offs,
    int2* __restrict__ sched1, int* __restrict__ idxl, float* __restrict__ wtl) {
  __shared__ int scan[256][8];
  __shared__ int loc[256][8];
  int tid = threadIdx.x;
#pragma unroll
  for (int e = 0; e < 8; e++) { scan[tid][e] = 0; loc[tid][e] = 0; }
  int t0 = tid * (T_TOK / 256);
  int4 raw[T_TOK / 256];
#pragma unroll
  for (int i = 0; i < T_TOK / 256; i++) {
    raw[i] = selraw[t0 + i];
    loc[tid][raw[i].x]++;
    loc[tid][raw[i].y]++;
  }
#pragma unroll
  for (int e = 0; e < 8; e++) scan[tid][e] = loc[tid][e];
  __syncthreads();
  for (int s = 1; s < 256; s <<= 1) {
    int v[8];
    if (tid >= s) {
#pragma unroll
      for (int e = 0; e < 8; e++) v[e] = scan[tid - s][e];
    }
    __syncthreads();
    if (tid >= s) {
#pragma unroll
      for (int e = 0; e < 8; e++) scan[tid][e] += v[e];
    }
    __syncthreads();
  }
  if (tid == 0) {
    int a = 0, t1 = 0;
    for (int e = 0; e < 8; e++) {
      int ce = scan[255][e];
      cnt[e] = ce; offs[e] = a; a += ce;
    }
    for (int e = 0; e < 8; e++)
      for (int b = 0; b < scan[255][e]; b += 128) sched1[t1++] = make_int2(e, b);
    for (; t1 < MAXT1; t1++) sched1[t1] = make_int2(-1, 0);
  }
#pragma unroll
  for (int e = 0; e < 8; e++) scan[tid][e] -= loc[tid][e];
  __syncthreads();
#pragma unroll
  for (int i = 0; i < T_TOK / 256; i++) {
    int t = t0 + i;
    int s1 = raw[i].x, s2 = raw[i].y;
    int p1 = scan[tid][s1]++;
    idxl[s1 * T_TOK + p1] = t;
    wtl[s1 * T_TOK + p1] = __int_as_float(raw[i].z);
    int p2 = scan[tid][s2]++;
    idxl[s2 * T_TOK + p2] = t;
    wtl[s2 * T_TOK + p2] = __int_as_float(raw[i].w);
  }
}

// ---------------- GEMM1: h = gelu(x@w1) * (x@w3) * wt ------------------------
// Tile 128M x 128N x BK32, 8 waves (2Mx4N, wave = 64Mx32N). 512 threads.
// 3-buffer counted-vmcnt pipeline: 3 gload16/wave/stage, vmcnt(3) in-loop.
// LDS unit(r,u) = r*4 + (u ^ ((r>>1)&3)) -> 2-way (free) on ds_read_b128.
#define STAGE1(b, kn) do { \
    gload16(gx + (kn), &Xs[b][(wv * 64 + lane) * 8]); \
    gload16(gw1 + (kn), &W1s[b][(wv * 64 + lane) * 8]); \
    gload16(gw3 + (kn), &W3s[b][(wv * 64 + lane) * 8]); \
  } while (0)

__global__ __launch_bounds__(512, 4) void gemm1_kernel(
    const ushort_t* __restrict__ xb, const ushort_t* __restrict__ w1t,
    const ushort_t* __restrict__ w3t, const int* __restrict__ idxl,
    const float* __restrict__ wtl, const int* __restrict__ cnt,
    const int* __restrict__ offs, const int2* __restrict__ sched,
    ushort_t* __restrict__ hbuf) {
  // expert-contiguous XCD mapping: XCD x owns m-tiles [9x, 9x+9)
  int bid = blockIdx.x;
  int xcd = bid & 7, j = bid >> 3;        // j in 0..71
  int mt = xcd * 9 + (j >> 3);
  int nb = j & 7;
  int2 sc = sched[mt];
  if (sc.x < 0) return;
  int e = sc.x, base = sc.y;
  int cnte = cnt[e], off0 = offs[e];
  int rows = min(128, cnte - base);
  int n0 = nb * 128;
  __shared__ ushort_t Xs[3][4096];    // 128 rows x 32 k (8 KB/buf)
  __shared__ ushort_t W1s[3][4096];
  __shared__ ushort_t W3s[3][4096];
  __shared__ int toks[128];
  __shared__ float wtls[128];
  int tid = threadIdx.x;
  if (tid < 128) {
    int r = min(tid, rows - 1);
    toks[tid] = idxl[e * T_TOK + base + r];
    wtls[tid] = (tid < rows) ? wtl[e * T_TOK + base + tid] : 0.f;
  }
  int lane = tid & 63, wv = tid >> 6;     // wv 0..7
  int wm = (wv >> 2) * 64, wn = (wv & 3) * 32;
  __syncthreads();

  int rS = wv * 16 + (lane >> 2);
  int us = ((lane & 3) ^ ((lane >> 3) & 3)) * 8;
  const ushort_t* gx  = xb + (size_t)toks[rS] * HDIM + us;
  const ushort_t* gw1 = w1t + ((size_t)e * FDIM + n0 + rS) * HDIM + us;
  const ushort_t* gw3 = w3t + ((size_t)e * FDIM + n0 + rS) * HDIM + us;

  f32x4 accU[4][2], accV[4][2];
#pragma unroll
  for (int m = 0; m < 4; m++)
#pragma unroll
    for (int n = 0; n < 2; n++) {
      accU[m][n] = {0.f, 0.f, 0.f, 0.f};
      accV[m][n] = {0.f, 0.f, 0.f, 0.f};
    }

  STAGE1(0, 0);
  STAGE1(1, 32);

  int uc = lane >> 4;  // 0..3
#pragma unroll
  for (int t = 0; t < 16; t++) {
    if (t < 15) asm volatile("s_waitcnt vmcnt(3)" ::: "memory");
    else        asm volatile("s_waitcnt vmcnt(0)" ::: "memory");
    __builtin_amdgcn_s_barrier();
    __builtin_amdgcn_sched_barrier(0);
    if (t < 14) STAGE1((t + 2) % 3, (t + 2) * 32);
    const int cur = t % 3;
    bf16x8 a[4], bu[2], bv[2];
#pragma unroll
    for (int m = 0; m < 4; m++) {
      int r = wm + m * 16 + (lane & 15);
      a[m] = __builtin_bit_cast(bf16x8,
          *reinterpret_cast<const uint4*>(&Xs[cur][(r * 4 + (uc ^ ((r >> 1) & 3))) * 8]));
    }
#pragma unroll
    for (int n = 0; n < 2; n++) {
      int r = wn + n * 16 + (lane & 15);
      bu[n] = __builtin_bit_cast(bf16x8,
          *reinterpret_cast<const uint4*>(&W1s[cur][(r * 4 + (uc ^ ((r >> 1) & 3))) * 8]));
      bv[n] = __builtin_bit_cast(bf16x8,
          *reinterpret_cast<const uint4*>(&W3s[cur][(r * 4 + (uc ^ ((r >> 1) & 3))) * 8]));
    }
#pragma unroll
    for (int m = 0; m < 4; m++)
#pragma unroll
      for (int n = 0; n < 2; n++) {
        accU[m][n] = __builtin_amdgcn_mfma_f32_16x16x32_bf16(a[m], bu[n], accU[m][n], 0, 0, 0);
        accV[m][n] = __builtin_amdgcn_mfma_f32_16x16x32_bf16(a[m], bv[n], accV[m][n], 0, 0, 0);
      }
  }

#pragma unroll
  for (int m = 0; m < 4; m++) {
#pragma unroll
    for (int rr = 0; rr < 4; rr++) {
      int row = wm + m * 16 + ((lane >> 4) << 2) + rr;
      if (row < rows) {
        float wgt = wtls[row];
        size_t po = (size_t)(off0 + base + row) * FDIM + n0 + wn + (lane & 15);
#pragma unroll
        for (int n = 0; n < 2; n++) {
          float u = accU[m][n][rr], v = accV[m][n][rr];
          float h = 0.5f * u * (1.0f + erff(u * 0.707106781186547524f)) * v * wgt;
          hbuf[po + n * 16] = (ushort_t)f2bf(h);
        }
      }
    }
  }
}

// ---------------- GEMM2: out[tok] += h @ w2  (contiguous slots) --------------
// Clone of gemm1's structure: 128M x 128N x BK32, 8 waves (2Mx4N), 512 threads,
// 3-buffer counted-vmcnt pipeline (2 gload16/wave/stage, vmcnt(2)), 32 K-steps.
// 48 KB LDS -> 3 blocks/CU. fp32 atomicAdd epilogue (2 commutative
// contributions per element -> deterministic).
#define STAGE2(b, kn) do { \
    gload16(ga + (kn), &As[b][(wv * 64 + lane) * 8]); \
    gload16(gb + (kn), &Bs[b][(wv * 64 + lane) * 8]); \
  } while (0)

__global__ __launch_bounds__(512, 4) void gemm2_kernel(
    const ushort_t* __restrict__ hbuf, const ushort_t* __restrict__ w2t,
    const int* __restrict__ idxl, const int* __restrict__ cnt,
    const int* __restrict__ offs, const int2* __restrict__ sched,
    float* __restrict__ out) {
  // expert-contiguous XCD mapping: XCD x owns m-tiles [9x, 9x+9); 4 n-blocks
  int bid = blockIdx.x;
  int xcd = bid & 7, j = bid >> 3;        // j in 0..35
  int mt = xcd * 9 + (j >> 2);
  int nb = j & 3;
  int2 sc = sched[mt];
  if (sc.x < 0) return;
  int e = sc.x, base = sc.y;
  int cnte = cnt[e], off0 = offs[e];
  int rows = min(128, cnte - base);
  int n0 = nb * 128;
  __shared__ ushort_t As[3][4096];   // 128 rows x 32 k (8 KB/buf)
  __shared__ ushort_t Bs[3][4096];   // 128 n-rows x 32 k
  __shared__ int toks[128];
  int tid = threadIdx.x;
  if (tid < 128) toks[tid] = idxl[e * T_TOK + base + min(tid, rows - 1)];
  int lane = tid & 63, wv = tid >> 6;     // wv 0..7
  int wm = (wv >> 2) * 64, wn = (wv & 3) * 32;
  __syncthreads();

  int rS = wv * 16 + (lane >> 2);
  int us = ((lane & 3) ^ ((lane >> 3) & 3)) * 8;
  const ushort_t* ga = hbuf + (size_t)(off0 + base + min(rS, rows - 1)) * FDIM + us;
  const ushort_t* gb = w2t + ((size_t)e * HDIM + n0 + rS) * FDIM + us;

  f32x4 acc[4][2];
#pragma unroll
  for (int m = 0; m < 4; m++)
#pragma unroll
    for (int n = 0; n < 2; n++) acc[m][n] = {0.f, 0.f, 0.f, 0.f};

  STAGE2(0, 0);
  STAGE2(1, 32);

  int uc = lane >> 4;  // 0..3
#pragma unroll
  for (int t = 0; t < 32; t++) {
    if (t < 31) asm volatile("s_waitcnt vmcnt(2)" ::: "memory");
    else        asm volatile("s_waitcnt vmcnt(0)" ::: "memory");
    __builtin_amdgcn_s_barrier();
    __builtin_amdgcn_sched_barrier(0);
    if (t < 30) STAGE2((t + 2) % 3, (t + 2) * 32);
    const int cur = t % 3;
    bf16x8 a[4], b[2];
#pragma unroll
    for (int m = 0; m < 4; m++) {
      int r = wm + m * 16 + (lane & 15);
      a[m] = __builtin_bit_cast(bf16x8,
          *reinterpret_cast<const uint4*>(&As[cur][(r * 4 + (uc ^ ((r >> 1) & 3))) * 8]));
    }
#pragma unroll
    for (int n = 0; n < 2; n++) {
      int r = wn + n * 16 + (lane & 15);
      b[n] = __builtin_bit_cast(bf16x8,
          *reinterpret_cast<const uint4*>(&Bs[cur][(r * 4 + (uc ^ ((r >> 1) & 3))) * 8]));
    }
#pragma unroll
    for (int m = 0; m < 4; m++)
#pragma unroll
      for (int n = 0; n < 2; n++)
        acc[m][n] = __builtin_amdgcn_mfma_f32_16x16x32_bf16(a[m], b[n], acc[m][n], 0, 0, 0);
  }

#pragma unroll
  for (int m = 0; m < 4; m++) {
#pragma unroll
    for (int rr = 0; rr < 4; rr++) {
      int row = wm + m * 16 + ((lane >> 4) << 2) + rr;
      if (row < rows) {
        int tok = toks[row];
        float* po = out + (size_t)tok * HDIM + n0 + wn + (lane & 15);
#pragma unroll
        for (int n = 0; n < 2; n++) atomicAdd(po + n * 16, acc[m][n][rr]);
      }
    }
  }
}

// ---------------- launch ----------------------------------------------------
extern "C" void kernel_launch(void* const* d_in, const int* in_sizes, int n_in,
                              void* d_out, int out_size, void* d_ws, size_t ws_size,
                              hipStream_t stream) {
  const float* x  = (const float*)d_in[0];
  const float* wg = (const float*)d_in[1];
  const float* bg = (const float*)d_in[2];
  const float* w1 = (const float*)d_in[3];
  const float* w3 = (const float*)d_in[4];
  const float* w2 = (const float*)d_in[5];
  float* out = (float*)d_out;
  char* ws = (char*)d_ws;

  int*   cnt    = (int*)(ws + 0);
  int*   offs   = (int*)(ws + 64);
  int2*  sched1 = (int2*)(ws + 128);                 // 576 B
  int4*  selraw = (int4*)(ws + 65536);               // 64 KB
  int*   idxl   = (int*)(ws + 131072);               // 128 KB
  float* wtl    = (float*)(ws + 262144);             // 128 KB
  ushort_t* xb   = (ushort_t*)(ws + (1ull << 20));   // 4 MB
  ushort_t* w1t  = (ushort_t*)(ws + (5ull << 20));   // 8 MB
  ushort_t* w3t  = (ushort_t*)(ws + (13ull << 20));  // 8 MB
  ushort_t* w2t  = (ushort_t*)(ws + (21ull << 20));  // 8 MB
  ushort_t* hbuf = (ushort_t*)(ws + (29ull << 20));  // 16 MB

  pre_kernel<<<1024 + 12288 + 2048, 256, 0, stream>>>(x, wg, bg, selraw, xb,
                                                      w1, w3, w2, w1t, w3t, w2t, out);
  build_kernel<<<1, 256, 0, stream>>>(selraw, cnt, offs, sched1, idxl, wtl);
  gemm1_kernel<<<8 * MAXT1, 512, 0, stream>>>(xb, w1t, w3t, idxl, wtl, cnt,
                                              offs, sched1, hbuf);
  gemm2_kernel<<<8 * 36, 512, 0, stream>>>(hbuf, w2t, idxl, cnt, offs,
                                           sched1, out);
}